// Round 4
// baseline (867.502 us; speedup 1.0000x reference)
//
#include <hip/hip_runtime.h>

// Problem constants (match reference)
#define V_TOT   200000
#define NPT     32
#define C_OUT   64
#define NXX     432
#define NYY     496
#define BB      8
#define NBUCK   512

static constexpr float kBnEps = 1e-3f;
static constexpr float kLnEps = 1e-3f;
static constexpr float kVX = 0.16f;
static constexpr float kVY = 0.16f;
static constexpr float kXOff = 0.08f;            // VX/2 + X_MIN (0.0)
static constexpr float kYOff = 0.08f - 39.68f;   // VY/2 + Y_MIN

// ---------------- Pass A: per-pillar PFN + scatter-index + LN-stats ----------
// 1 wave (64 lanes) per pillar; lane = output channel. 4 pillars / 256-thr block.
__global__ __launch_bounds__(256) void pillar_kernel(
    const float* __restrict__ voxels,      // [V, 32, 4]
    const int*   __restrict__ num_points,  // [V]
    const int*   __restrict__ coors,       // [V, 4]
    const float* __restrict__ w,           // [9, 64]
    const float* __restrict__ bn_gamma, const float* __restrict__ bn_beta,
    const float* __restrict__ bn_mean,  const float* __restrict__ bn_var,
    float* __restrict__ xmax,              // [V, 64]
    int*   __restrict__ idx,               // [B*NY*NX], pre-init -1
    float* __restrict__ ssum,              // [B, NBUCK]
    float* __restrict__ ssq)               // [B, NBUCK]
{
  __shared__ float2 pts2[4][64];           // per-wave: 32 points x (xy),(zr)
  const int tid  = threadIdx.x;
  const int wv   = tid >> 6;
  const int lane = tid & 63;
  const int p    = blockIdx.x * 4 + wv;

  // stage 32x4 floats = 64 float2 per pillar, coalesced
  const float2* vsrc = reinterpret_cast<const float2*>(voxels + (size_t)p * (NPT * 4));
  pts2[wv][lane] = vsrc[lane];
  __syncthreads();

  const int npts = num_points[p];
  const int b    = coors[p * 4 + 0];
  const int yy   = coors[p * 4 + 2];
  const int xx   = coors[p * 4 + 3];

  // cluster mean over valid points (butterfly across 64 lanes; lanes>=npts contribute 0)
  float sx = 0.f, sy = 0.f, sz = 0.f;
  if (lane < npts) {
    float2 a  = pts2[wv][2 * lane];
    float2 bq = pts2[wv][2 * lane + 1];
    sx = a.x; sy = a.y; sz = bq.x;
  }
  #pragma unroll
  for (int off = 32; off; off >>= 1) {
    sx += __shfl_xor(sx, off);
    sy += __shfl_xor(sy, off);
    sz += __shfl_xor(sz, off);
  }
  const float npf = (float)npts;
  const float mx = sx / npf, my = sy / npf, mz = sz / npf;

  // per-lane channel weights; collapse 9-feature dot into 4 coords + constant K
  const float w0 = w[0 * 64 + lane], w1 = w[1 * 64 + lane], w2 = w[2 * 64 + lane];
  const float w3 = w[3 * 64 + lane], w4 = w[4 * 64 + lane], w5 = w[5 * 64 + lane];
  const float w6 = w[6 * 64 + lane], w7 = w[7 * 64 + lane], w8 = w[8 * 64 + lane];
  const float W0 = w0 + w4 + w7;
  const float W1 = w1 + w5 + w8;
  const float W2 = w2 + w6;
  const float W3 = w3;
  const float cx = fmaf((float)xx, kVX, kXOff);
  const float cy = fmaf((float)yy, kVY, kYOff);
  const float K  = -(mx * w4 + my * w5 + mz * w6 + cx * w7 + cy * w8);

  float dmax = -3.402823466e38f, dmin = 3.402823466e38f;
  for (int n = 0; n < npts; ++n) {
    float2 a  = pts2[wv][2 * n];       // broadcast LDS reads (no bank conflict)
    float2 bq = pts2[wv][2 * n + 1];
    float t = fmaf(a.x, W0, fmaf(a.y, W1, fmaf(bq.x, W2, bq.y * W3)));
    dmax = fmaxf(dmax, t);
    dmin = fminf(dmin, t);
  }
  dmax += K;
  dmin += K;
  if (npts < NPT) {                    // masked slots have dot == 0 exactly
    dmax = fmaxf(dmax, 0.f);
    dmin = fminf(dmin, 0.f);
  }
  const float ac = bn_gamma[lane] * rsqrtf(bn_var[lane] + kBnEps);
  const float bc = fmaf(-bn_mean[lane], ac, bn_beta[lane]);
  const float d  = (ac >= 0.f) ? dmax : dmin;   // affine+relu monotone => max commutes
  const float val = fmaxf(fmaf(ac, d, bc), 0.f);

  xmax[(size_t)p * 64 + lane] = val;

  // LN statistics: wave-reduce then one atomic pair per pillar, bucket-spread
  float s1 = val, s2 = val * val;
  #pragma unroll
  for (int off = 32; off; off >>= 1) {
    s1 += __shfl_xor(s1, off);
    s2 += __shfl_xor(s2, off);
  }
  if (lane == 0) {
    const int bucket = blockIdx.x & (NBUCK - 1);
    atomicAdd(&ssum[b * NBUCK + bucket], s1);
    atomicAdd(&ssq[b * NBUCK + bucket], s2);
    idx[(size_t)b * (NYY * NXX) + yy * NXX + xx] = p;
  }
}

// ---------------- Pass B: reduce buckets -> per-batch mu, rsqrt(var+eps) -----
__global__ __launch_bounds__(512) void stats_kernel(
    const float* __restrict__ ssum, const float* __restrict__ ssq,
    float* __restrict__ murs)  // [16]: mu[8], rs[8]
{
  const int bw   = threadIdx.x >> 6;   // wave = batch
  const int lane = threadIdx.x & 63;
  float s1 = 0.f, s2 = 0.f;
  for (int j = lane; j < NBUCK; j += 64) {
    s1 += ssum[bw * NBUCK + j];
    s2 += ssq[bw * NBUCK + j];
  }
  #pragma unroll
  for (int off = 32; off; off >>= 1) {
    s1 += __shfl_xor(s1, off);
    s2 += __shfl_xor(s2, off);
  }
  if (lane == 0) {
    const float M  = 64.f * 496.f * 432.f;
    const float mu = s1 / M;
    const float vr = fmaxf(s2 / M - mu * mu, 0.f);
    murs[bw]     = mu;
    murs[8 + bw] = rsqrtf(vr + kLnEps);
  }
}

// ---------------- Pass C: dense normalized BEV output ------------------------
// 1 block per (b, y) row: 432 cells x 64 channels. Coalesced lnw/lnb/out.
__global__ __launch_bounds__(256) void out_kernel(
    const float* __restrict__ xmax, const int* __restrict__ idx,
    const float* __restrict__ murs,
    const float* __restrict__ lnw, const float* __restrict__ lnb,
    float* __restrict__ out)
{
  __shared__ int idx_row[NXX];
  const int bid = blockIdx.x;
  const int b = bid / NYY;
  const int y = bid % NYY;
  const int tid = threadIdx.x;

  for (int i = tid; i < NXX; i += 256)
    idx_row[i] = idx[(size_t)b * (NYY * NXX) + y * NXX + i];
  __syncthreads();

  const float mu = murs[b];
  const float rs = murs[8 + b];
  const int g = tid >> 6;      // channel sub-group 0..3
  const int l = tid & 63;      // x within 64-chunk

  #pragma unroll
  for (int cb = 0; cb < 16; ++cb) {
    const int c = cb * 4 + g;
    const size_t obase = ((size_t)(b * 64 + c) * NYY + y) * NXX;
    const size_t lbase = ((size_t)c * NYY + y) * NXX;
    #pragma unroll
    for (int xb = 0; xb < 7; ++xb) {
      const int x = xb * 64 + l;
      if (x < NXX) {
        const int p = idx_row[x];
        const float v = (p >= 0) ? xmax[(size_t)p * 64 + c] : 0.f;
        out[obase + x] = fmaf((v - mu) * rs, lnw[lbase + x], lnb[lbase + x]);
      }
    }
  }
}

extern "C" void kernel_launch(void* const* d_in, const int* in_sizes, int n_in,
                              void* d_out, int out_size, void* d_ws, size_t ws_size,
                              hipStream_t stream) {
  const float* voxels     = (const float*)d_in[0];
  const int*   num_points = (const int*)d_in[1];
  const int*   coors      = (const int*)d_in[2];
  const float* w          = (const float*)d_in[3];
  const float* bn_gamma   = (const float*)d_in[4];
  const float* bn_beta    = (const float*)d_in[5];
  const float* bn_mean    = (const float*)d_in[6];
  const float* bn_var     = (const float*)d_in[7];
  const float* ln_w       = (const float*)d_in[8];
  const float* ln_b       = (const float*)d_in[9];
  float* out = (float*)d_out;

  char* ws = (char*)d_ws;
  float* xmax = (float*)ws;                                 // 200000*64*4 = 51,200,000 B
  int*   idx  = (int*)(ws + 51200000);                      //  6,856,704 B
  float* ssum = (float*)(ws + 58056704);                    // 8*512*4 = 16,384 B
  float* ssq  = (float*)(ws + 58056704 + 16384);            // 16,384 B
  float* murs = (float*)(ws + 58056704 + 32768);            // 64 B

  hipMemsetAsync(idx, 0xFF, (size_t)BB * NYY * NXX * sizeof(int), stream);  // -1
  hipMemsetAsync(ssum, 0, 2 * BB * NBUCK * sizeof(float) + 64, stream);

  pillar_kernel<<<V_TOT / 4, 256, 0, stream>>>(
      voxels, num_points, coors, w, bn_gamma, bn_beta, bn_mean, bn_var,
      xmax, idx, ssum, ssq);
  stats_kernel<<<1, 512, 0, stream>>>(ssum, ssq, murs);
  out_kernel<<<BB * NYY, 256, 0, stream>>>(xmax, idx, murs, ln_w, ln_b, out);
}